// Round 1
// baseline (1053.033 us; speedup 1.0000x reference)
//
#include <hip/hip_runtime.h>
#include <stdint.h>

#define CC 128
#define HH 192
#define WW 512
#define BB 2
#define HW (HH*WW)
#define CHW (CC*HW)
#define TENS (BB*CHW)   // 25165824 elems per [B,C,H,W] tensor

typedef __attribute__((ext_vector_type(8))) short bf16x8;
typedef __attribute__((ext_vector_type(4))) float f32x4;

__device__ __forceinline__ unsigned short f2bf(float f) {
    union { float f; unsigned u; } v; v.f = f;
    return (unsigned short)((v.u + 0x7FFFu + ((v.u >> 16) & 1u)) >> 16);
}

__device__ __forceinline__ f32x4 MFMA(bf16x8 a, bf16x8 b, f32x4 c) {
    return __builtin_amdgcn_mfma_f32_16x16x32_bf16(a, b, c, 0, 0, 0);
}

// ---------------- weight transpose: dl_w/dr_w [O][C][3][3] -> [side][tap][o][c] bf16
__global__ __launch_bounds__(256) void wcast_k(
    const float* __restrict__ dlw, const float* __restrict__ drw,
    unsigned short* __restrict__ wd)
{
    int i = blockIdx.x * 256 + threadIdx.x;
    if (i >= 2 * 9 * CC * CC) return;
    int side = i / (9 * CC * CC);
    int r = i % (9 * CC * CC);
    int tap = r / (CC * CC);
    int r2 = r % (CC * CC);
    int o = r2 >> 7, c = r2 & 127;
    const float* src = side ? drw : dlw;
    wd[i] = f2bf(src[((size_t)o * CC + c) * 9 + tap]);
}

// ---------------- LayerNorm over C, write N transposed [B,H,W,C] bf16
__global__ __launch_bounds__(256) void ln_k(
    const float* __restrict__ xl, const float* __restrict__ xr,
    const float* __restrict__ nlw, const float* __restrict__ nlb,
    const float* __restrict__ nrw, const float* __restrict__ nrb,
    unsigned short* __restrict__ ntl, unsigned short* __restrict__ ntr)
{
    const int side = blockIdx.y;
    const float* x  = side ? xr : xl;
    const float* wl = side ? nrw : nlw;
    const float* bl = side ? nrb : nlb;
    unsigned short* nt = side ? ntr : ntl;
    const int bid = blockIdx.x;
    const int wt = bid & 7, h = (bid >> 3) % HH, b = bid / (8 * HH);
    const int w0 = wt * 64;
    const int t = threadIdx.x;

    __shared__ float tile[CC][65];
    __shared__ float psum[4][64];
    __shared__ float psq[4][64];
    __shared__ float smu[64];
    __shared__ float srs[64];

    {
        const int w = t & 63, cg = t >> 6;
        const float* xp = x + (size_t)b * CHW + (size_t)h * WW + w0 + w;
        float s = 0.f, q = 0.f;
        for (int i = 0; i < 32; i++) {
            int c = cg * 32 + i;
            float v = xp[(size_t)c * HW];
            tile[c][w] = v;
            s += v; q += v * v;
        }
        psum[cg][w] = s; psq[cg][w] = q;
    }
    __syncthreads();
    if (t < 64) {
        float S = psum[0][t] + psum[1][t] + psum[2][t] + psum[3][t];
        float Q = psq[0][t] + psq[1][t] + psq[2][t] + psq[3][t];
        float mu = S * (1.f / CC);
        float var = fmaxf(Q * (1.f / CC) - mu * mu, 0.f);
        smu[t] = mu;
        srs[t] = rsqrtf(var + 1e-6f);
    }
    __syncthreads();
    {
        const int w = t >> 2, c0 = (t & 3) * 32;
        const float mu = smu[w], rs = srs[w];
        unsigned short* np = nt + ((size_t)(b * HH + h) * WW + w0 + w) * CC;
        for (int i = 0; i < 32; i += 2) {
            int c = c0 + i;
            float v0 = (tile[c][w] - mu) * rs * wl[c] + bl[c];
            float v1 = (tile[c + 1][w] - mu) * rs * wl[c + 1] + bl[c + 1];
            ushort2 u; u.x = f2bf(v0); u.y = f2bf(v1);
            *(ushort2*)&np[c] = u;
        }
    }
}

// ---------------- V = conv1x1(x, lp2/rp2) -> [B,H,W,C] bf16 (reads x fp32 directly)
__global__ __launch_bounds__(256) void vgemm_k(
    const float* __restrict__ xl, const float* __restrict__ xr,
    const float* __restrict__ wlp, const float* __restrict__ blp,
    const float* __restrict__ wrp, const float* __restrict__ brp,
    unsigned short* __restrict__ vlo, unsigned short* __restrict__ vro)
{
    const int side = blockIdx.y;
    const float* x  = side ? xr : xl;
    const float* wv = side ? wrp : wlp;
    const float* bv = side ? brp : blp;
    unsigned short* vo = side ? vro : vlo;
    const int bid = blockIdx.x;
    const int wt = bid & 7, h = (bid >> 3) % HH, b = bid / (8 * HH);
    const int w0 = wt * 64;
    const int t = threadIdx.x;

    __shared__ unsigned short sA[64][136];    // x^T tile [w][c] bf16
    __shared__ unsigned short sB[128][136];   // weight [o][c] bf16

    {
        const int w = t & 63;
        const float* xp = x + (size_t)b * CHW + (size_t)h * WW + w0 + w;
        for (int i = 0; i < 32; i++) {
            int c = (t >> 6) + i * 4;
            sA[w][c] = f2bf(xp[(size_t)c * HW]);
        }
    }
    for (int it = 0; it < 16; it++) {
        int f = it * 1024 + t * 4;
        int o = f >> 7, c = f & 127;
        float4 v = *(const float4*)(wv + o * CC + c);
        sB[o][c] = f2bf(v.x); sB[o][c + 1] = f2bf(v.y);
        sB[o][c + 2] = f2bf(v.z); sB[o][c + 3] = f2bf(v.w);
    }
    __syncthreads();
    const int wid = t >> 6, l = t & 63, lr = l & 15, lg = l >> 4;
    f32x4 acc[8] = {};
    for (int kk = 0; kk < 4; kk++) {
        bf16x8 a = *(const bf16x8*)&sA[wid * 16 + lr][kk * 32 + lg * 8];
#pragma unroll
        for (int nt = 0; nt < 8; nt++) {
            bf16x8 bb = *(const bf16x8*)&sB[nt * 16 + lr][kk * 32 + lg * 8];
            acc[nt] = MFMA(a, bb, acc[nt]);
        }
    }
    unsigned short* vp = vo + ((size_t)(b * HH + h) * WW + w0) * CC;
    for (int nt = 0; nt < 8; nt++) {
        int o = nt * 16 + lr;
        float bias = bv[o];
        for (int j = 0; j < 4; j++) {
            int w = wid * 16 + lg * 4 + j;
            vp[(size_t)w * CC + o] = f2bf(acc[nt][j] + bias);
        }
    }
}

// ---------------- K = dilated 3x3 conv (dilation 4, pad 4) over N -> [B,H,W,C] bf16
__global__ __launch_bounds__(256) void dconv_k(
    const unsigned short* __restrict__ ntl, const unsigned short* __restrict__ ntr,
    const unsigned short* __restrict__ wd,
    const float* __restrict__ dlb, const float* __restrict__ drb,
    unsigned short* __restrict__ klo, unsigned short* __restrict__ kro)
{
    const int side = blockIdx.y;
    const unsigned short* nt = side ? ntr : ntl;
    const unsigned short* wdp = wd + (size_t)side * 9 * CC * CC;
    const float* bd = side ? drb : dlb;
    unsigned short* ko = side ? kro : klo;
    const int bid = blockIdx.x;
    const int wt = bid & 7, h = (bid >> 3) % HH, b = bid / (8 * HH);
    const int w0 = wt * 64;
    const int t = threadIdx.x;
    const int wid = t >> 6, l = t & 63, lr = l & 15, lg = l >> 4;

    __shared__ unsigned short sA[72][136];    // one dy-row of N, w0-4 .. w0+67
    __shared__ unsigned short sB[128][136];   // one tap's weights [o][c]

    f32x4 acc[8] = {};
    for (int dy = 0; dy < 3; dy++) {
        const int hh = h + 4 * (dy - 1);
        const bool hok = (hh >= 0 && hh < HH);
        __syncthreads();
        for (int f = t * 8; f < 72 * 128; f += 2048) {
            int wloc = f >> 7, c = f & 127;
            int w = w0 - 4 + wloc;
            bf16x8 v = {0, 0, 0, 0, 0, 0, 0, 0};
            if (hok && w >= 0 && w < WW)
                v = *(const bf16x8*)(nt + ((size_t)(b * HH + hh) * WW + w) * CC + c);
            *(bf16x8*)&sA[wloc][c] = v;
        }
        for (int dx = 0; dx < 3; dx++) {
            __syncthreads();
            const int tap = dy * 3 + dx;
            for (int it = 0; it < 8; it++) {
                int f = it * 2048 + t * 8;
                *(bf16x8*)&sB[f >> 7][f & 127] =
                    *(const bf16x8*)(wdp + (size_t)tap * CC * CC + f);
            }
            __syncthreads();
            const int arow = wid * 16 + lr + 4 * dx;
            for (int kk = 0; kk < 4; kk++) {
                bf16x8 a = *(const bf16x8*)&sA[arow][kk * 32 + lg * 8];
#pragma unroll
                for (int nt_ = 0; nt_ < 8; nt_++) {
                    bf16x8 bb = *(const bf16x8*)&sB[nt_ * 16 + lr][kk * 32 + lg * 8];
                    acc[nt_] = MFMA(a, bb, acc[nt_]);
                }
            }
        }
    }
    unsigned short* kp = ko + ((size_t)(b * HH + h) * WW + w0) * CC;
    for (int nt_ = 0; nt_ < 8; nt_++) {
        int o = nt_ * 16 + lr;
        float bias = bd[o];
        for (int j = 0; j < 4; j++) {
            int w = wid * 16 + lg * 4 + j;
            kp[(size_t)w * CC + o] = f2bf(acc[nt_][j] + bias);
        }
    }
}

// ---------------- fused Q-GEMM + flash attention + residual epilogue
__global__ __launch_bounds__(256) void attn_k(
    const unsigned short* __restrict__ ntl, const unsigned short* __restrict__ ntr,
    const unsigned short* __restrict__ kl,  const unsigned short* __restrict__ kr,
    const unsigned short* __restrict__ vl,  const unsigned short* __restrict__ vr,
    const float* __restrict__ lp1w, const float* __restrict__ lp1b,
    const float* __restrict__ rp1w, const float* __restrict__ rp1b,
    const float* __restrict__ xl, const float* __restrict__ xr,
    const float* __restrict__ beta, const float* __restrict__ gamma,
    float* __restrict__ out)
{
    __shared__ __align__(16) char smem[61440];
    unsigned short* sQ  = (unsigned short*)smem;             // [64][136] N tile -> Q bf16
    unsigned short* sW  = (unsigned short*)(smem + 17408);   // [128][136] Wq
    unsigned short* sKt = sW;                                // [64][136] K tile
    unsigned short* sVt = (unsigned short*)(smem + 34816);   // [128][64] V^T swizzled
    unsigned short* sPs = (unsigned short*)(smem + 52224);   // [64][72] P bf16
    float* sOf = (float*)(smem + 17408);                     // [64][129] O fp32 (epilogue)

    const int dir = blockIdx.z;
    const unsigned short* nq  = dir ? ntr : ntl;
    const unsigned short* kws = dir ? kl : kr;
    const unsigned short* vws = dir ? vl : vr;
    const float* wq   = dir ? rp1w : lp1w;
    const float* bq   = dir ? rp1b : lp1b;
    const float* xres = dir ? xr : xl;
    const float* mult = dir ? gamma : beta;
    float* op = out + (size_t)dir * TENS;

    const int bh = blockIdx.y;          // b*H + h
    const int q0 = blockIdx.x * 64;
    const int t = threadIdx.x;
    const int wid = t >> 6, l = t & 63, lr = l & 15, lg = l >> 4;

    // ---- Phase A: stage N tile + Wq, compute Q = (N*Wq + b) * scale * log2e ----
    {
        const unsigned short* nsrc = nq + ((size_t)bh * WW + q0) * CC;
        for (int it = 0; it < 4; it++) {
            int f = it * 2048 + t * 8;
            *(bf16x8*)&sQ[(f >> 7) * 136 + (f & 127)] = *(const bf16x8*)(nsrc + f);
        }
        for (int it = 0; it < 16; it++) {
            int f = it * 1024 + t * 4;
            int o = f >> 7, c = f & 127;
            float4 v = *(const float4*)(wq + o * CC + c);
            unsigned short* p = &sW[o * 136 + c];
            p[0] = f2bf(v.x); p[1] = f2bf(v.y); p[2] = f2bf(v.z); p[3] = f2bf(v.w);
        }
    }
    __syncthreads();
    f32x4 qacc[8] = {};
    for (int kk = 0; kk < 4; kk++) {
        bf16x8 a = *(const bf16x8*)&sQ[(wid * 16 + lr) * 136 + kk * 32 + lg * 8];
#pragma unroll
        for (int nt = 0; nt < 8; nt++) {
            bf16x8 b = *(const bf16x8*)&sW[(nt * 16 + lr) * 136 + kk * 32 + lg * 8];
            qacc[nt] = MFMA(a, b, qacc[nt]);
        }
    }
    const float SCL = 0.08838834764831845f * 1.4426950408889634f;  // C^-0.5 * log2e
    for (int nt = 0; nt < 8; nt++) {
        float bias = bq[nt * 16 + lr];
        for (int j = 0; j < 4; j++)
            sQ[(wid * 16 + lg * 4 + j) * 136 + nt * 16 + lr] =
                f2bf((qacc[nt][j] + bias) * SCL);
    }
    __syncthreads();
    bf16x8 qf[4];
#pragma unroll
    for (int kk = 0; kk < 4; kk++)
        qf[kk] = *(const bf16x8*)&sQ[(wid * 16 + lr) * 136 + kk * 32 + lg * 8];

    // ---- Phase B: online-softmax attention over 8 KV tiles of 64 ----
    f32x4 oacc[8] = {};
    float mrow[4] = {-1e30f, -1e30f, -1e30f, -1e30f};
    float lrow[4] = {0.f, 0.f, 0.f, 0.f};
    const unsigned short* ksrc = kws + (size_t)bh * WW * CC;
    const unsigned short* vsrc = vws + (size_t)bh * WW * CC;

    for (int kb = 0; kb < 8; kb++) {
        __syncthreads();
        for (int it = 0; it < 4; it++) {
            int f = it * 2048 + t * 8;
            *(bf16x8*)&sKt[(f >> 7) * 136 + (f & 127)] =
                *(const bf16x8*)(ksrc + kb * 64 * CC + f);
        }
        for (int it = 0; it < 4; it++) {
            int f = it * 2048 + t * 8;
            int kloc = f >> 7, c = f & 127;
            bf16x8 v = *(const bf16x8*)(vsrc + kb * 64 * CC + f);
            int kc = kloc >> 3, kbit = kloc & 7;
#pragma unroll
            for (int i = 0; i < 8; i++) {
                int cc = c + i;
                sVt[cc * 64 + ((kc ^ (cc & 7)) << 3) + kbit] = (unsigned short)v[i];
            }
        }
        __syncthreads();
        f32x4 sacc[4] = {};
        for (int kk = 0; kk < 4; kk++)
#pragma unroll
            for (int nt = 0; nt < 4; nt++) {
                bf16x8 b = *(const bf16x8*)&sKt[(nt * 16 + lr) * 136 + kk * 32 + lg * 8];
                sacc[nt] = MFMA(qf[kk], b, sacc[nt]);
            }
        float al[4];
        for (int j = 0; j < 4; j++) {
            float mx = fmaxf(fmaxf(sacc[0][j], sacc[1][j]), fmaxf(sacc[2][j], sacc[3][j]));
            for (int d = 1; d < 16; d <<= 1) mx = fmaxf(mx, __shfl_xor(mx, d, 64));
            float mn = fmaxf(mrow[j], mx);
            al[j] = exp2f(mrow[j] - mn);
            mrow[j] = mn;
            float rs = 0.f;
            for (int nt = 0; nt < 4; nt++) {
                float p = exp2f(sacc[nt][j] - mn);
                sacc[nt][j] = p;
                rs += p;
            }
            for (int d = 1; d < 16; d <<= 1) rs += __shfl_xor(rs, d, 64);
            lrow[j] = lrow[j] * al[j] + rs;
        }
        for (int nt = 0; nt < 8; nt++) {
            f32x4 o = oacc[nt];
            o[0] *= al[0]; o[1] *= al[1]; o[2] *= al[2]; o[3] *= al[3];
            oacc[nt] = o;
        }
        for (int nt = 0; nt < 4; nt++)
            for (int j = 0; j < 4; j++)
                sPs[(wid * 16 + lg * 4 + j) * 72 + nt * 16 + lr] = f2bf(sacc[nt][j]);
        __syncthreads();
        for (int kk = 0; kk < 2; kk++) {
            bf16x8 pa = *(const bf16x8*)&sPs[(wid * 16 + lr) * 72 + kk * 32 + lg * 8];
#pragma unroll
            for (int nt = 0; nt < 8; nt++) {
                int cc = nt * 16 + lr;
                int kc = (4 * kk + lg) ^ (cc & 7);
                bf16x8 vb = *(const bf16x8*)&sVt[cc * 64 + kc * 8];
                oacc[nt] = MFMA(pa, vb, oacc[nt]);
            }
        }
    }

    // ---- epilogue: normalize, transpose through LDS, residual + scale, store ----
    for (int j = 0; j < 4; j++) {
        float inv = 1.f / lrow[j];
        for (int nt = 0; nt < 8; nt++) oacc[nt][j] *= inv;
    }
    __syncthreads();
    for (int nt = 0; nt < 8; nt++)
        for (int j = 0; j < 4; j++)
            sOf[(wid * 16 + lg * 4 + j) * 129 + nt * 16 + lr] = oacc[nt][j];
    __syncthreads();
    const int b = bh / HH, h = bh % HH;
    const float* xp = xres + (size_t)b * CHW + (size_t)h * WW + q0;
    float* outp = op + (size_t)b * CHW + (size_t)h * WW + q0;
    const int w = t & 63;
    for (int i = 0; i < 32; i++) {
        int c = (t >> 6) + i * 4;
        outp[(size_t)c * HW + w] = xp[(size_t)c * HW + w] + sOf[w * 129 + c] * mult[c];
    }
}

extern "C" void kernel_launch(void* const* d_in, const int* in_sizes, int n_in,
                              void* d_out, int out_size, void* d_ws, size_t ws_size,
                              hipStream_t stream)
{
    const float* xl   = (const float*)d_in[0];
    const float* xr   = (const float*)d_in[1];
    const float* nlw  = (const float*)d_in[2];
    const float* nlb  = (const float*)d_in[3];
    const float* nrw  = (const float*)d_in[4];
    const float* nrb  = (const float*)d_in[5];
    const float* lp1w = (const float*)d_in[6];
    const float* lp1b = (const float*)d_in[7];
    const float* rp1w = (const float*)d_in[8];
    const float* rp1b = (const float*)d_in[9];
    const float* dlw  = (const float*)d_in[10];
    const float* dlb  = (const float*)d_in[11];
    const float* drw  = (const float*)d_in[12];
    const float* drb  = (const float*)d_in[13];
    const float* lp2w = (const float*)d_in[14];
    const float* lp2b = (const float*)d_in[15];
    const float* rp2w = (const float*)d_in[16];
    const float* rp2b = (const float*)d_in[17];
    const float* beta = (const float*)d_in[18];
    const float* gamma= (const float*)d_in[19];
    float* out = (float*)d_out;

    unsigned short* ws = (unsigned short*)d_ws;
    const size_t A = (size_t)TENS;
    unsigned short* Ntl = ws;
    unsigned short* Ntr = ws + A;
    unsigned short* Kl  = ws + 2 * A;
    unsigned short* Kr  = ws + 3 * A;
    unsigned short* Vl  = ws + 4 * A;
    unsigned short* Vr  = ws + 5 * A;
    unsigned short* Wd  = ws + 6 * A;     // [2][9][128][128] bf16

    wcast_k<<<dim3(1152), 256, 0, stream>>>(dlw, drw, Wd);
    ln_k<<<dim3(3072, 2), 256, 0, stream>>>(xl, xr, nlw, nlb, nrw, nrb, Ntl, Ntr);
    vgemm_k<<<dim3(3072, 2), 256, 0, stream>>>(xl, xr, lp2w, lp2b, rp2w, rp2b, Vl, Vr);
    dconv_k<<<dim3(3072, 2), 256, 0, stream>>>(Ntl, Ntr, Wd, dlb, drb, Kl, Kr);
    attn_k<<<dim3(8, 384, 2), 256, 0, stream>>>(Ntl, Ntr, Kl, Kr, Vl, Vr,
        lp1w, lp1b, rp1w, rp1b, xl, xr, beta, gamma, out);
}

// Round 2
// 766.479 us; speedup vs baseline: 1.3739x; 1.3739x over previous
//
#include <hip/hip_runtime.h>
#include <stdint.h>

#define CC 128
#define HH 192
#define WW 512
#define BB 2
#define HW (HH*WW)
#define CHW (CC*HW)
#define TENS (BB*CHW)   // 25165824 elems per [B,C,H,W] tensor

typedef __attribute__((ext_vector_type(8))) short bf16x8;
typedef __attribute__((ext_vector_type(4))) float f32x4;
typedef __attribute__((ext_vector_type(4))) unsigned short u16x4;

__device__ __forceinline__ unsigned short f2bf(float f) {
    union { float f; unsigned u; } v; v.f = f;
    return (unsigned short)((v.u + 0x7FFFu + ((v.u >> 16) & 1u)) >> 16);
}

__device__ __forceinline__ f32x4 MFMA(bf16x8 a, bf16x8 b, f32x4 c) {
    return __builtin_amdgcn_mfma_f32_16x16x32_bf16(a, b, c, 0, 0, 0);
}

// ---------------- weight transpose: dl_w/dr_w [O][C][3][3] -> [side][tap][o][c] bf16
__global__ __launch_bounds__(256) void wcast_k(
    const float* __restrict__ dlw, const float* __restrict__ drw,
    unsigned short* __restrict__ wd)
{
    int i = blockIdx.x * 256 + threadIdx.x;
    if (i >= 2 * 9 * CC * CC) return;
    int side = i / (9 * CC * CC);
    int r = i % (9 * CC * CC);
    int tap = r / (CC * CC);
    int r2 = r % (CC * CC);
    int o = r2 >> 7, c = r2 & 127;
    const float* src = side ? drw : dlw;
    wd[i] = f2bf(src[((size_t)o * CC + c) * 9 + tap]);
}

// ---------------- LayerNorm over C, write N transposed [B,H,W,C] bf16
__global__ __launch_bounds__(256) void ln_k(
    const float* __restrict__ xl, const float* __restrict__ xr,
    const float* __restrict__ nlw, const float* __restrict__ nlb,
    const float* __restrict__ nrw, const float* __restrict__ nrb,
    unsigned short* __restrict__ ntl, unsigned short* __restrict__ ntr)
{
    const int side = blockIdx.y;
    const float* x  = side ? xr : xl;
    const float* wl = side ? nrw : nlw;
    const float* bl = side ? nrb : nlb;
    unsigned short* nt = side ? ntr : ntl;
    const int bid = blockIdx.x;
    const int wt = bid & 7, h = (bid >> 3) % HH, b = bid / (8 * HH);
    const int w0 = wt * 64;
    const int t = threadIdx.x;

    __shared__ float tile[CC][65];
    __shared__ float psum[4][64];
    __shared__ float psq[4][64];
    __shared__ float smu[64];
    __shared__ float srs[64];

    {
        const int w = t & 63, cg = t >> 6;
        const float* xp = x + (size_t)b * CHW + (size_t)h * WW + w0 + w;
        float s = 0.f, q = 0.f;
        for (int i = 0; i < 32; i++) {
            int c = cg * 32 + i;
            float v = xp[(size_t)c * HW];
            tile[c][w] = v;
            s += v; q += v * v;
        }
        psum[cg][w] = s; psq[cg][w] = q;
    }
    __syncthreads();
    if (t < 64) {
        float S = psum[0][t] + psum[1][t] + psum[2][t] + psum[3][t];
        float Q = psq[0][t] + psq[1][t] + psq[2][t] + psq[3][t];
        float mu = S * (1.f / CC);
        float var = fmaxf(Q * (1.f / CC) - mu * mu, 0.f);
        smu[t] = mu;
        srs[t] = rsqrtf(var + 1e-6f);
    }
    __syncthreads();
    {
        const int w = t >> 2, c0 = (t & 3) * 32;
        const float mu = smu[w], rs = srs[w];
        unsigned short* np = nt + ((size_t)(b * HH + h) * WW + w0 + w) * CC;
        for (int i = 0; i < 32; i += 2) {
            int c = c0 + i;
            float v0 = (tile[c][w] - mu) * rs * wl[c] + bl[c];
            float v1 = (tile[c + 1][w] - mu) * rs * wl[c + 1] + bl[c + 1];
            ushort2 u; u.x = f2bf(v0); u.y = f2bf(v1);
            *(ushort2*)&np[c] = u;
        }
    }
}

// ---------------- V = conv1x1(x, lp2/rp2) -> V^T layout [B,H,C,W] bf16
__global__ __launch_bounds__(256) void vgemm_k(
    const float* __restrict__ xl, const float* __restrict__ xr,
    const float* __restrict__ wlp, const float* __restrict__ blp,
    const float* __restrict__ wrp, const float* __restrict__ brp,
    unsigned short* __restrict__ vlo, unsigned short* __restrict__ vro)
{
    const int side = blockIdx.y;
    const float* x  = side ? xr : xl;
    const float* wv = side ? wrp : wlp;
    const float* bv = side ? brp : blp;
    unsigned short* vo = side ? vro : vlo;
    const int bid = blockIdx.x;
    const int wt = bid & 7, h = (bid >> 3) % HH, b = bid / (8 * HH);
    const int w0 = wt * 64;
    const int t = threadIdx.x;

    __shared__ unsigned short sA[64][136];    // x^T tile [w][c] bf16
    __shared__ unsigned short sB[128][136];   // weight [o][c] bf16

    {
        const int w = t & 63;
        const float* xp = x + (size_t)b * CHW + (size_t)h * WW + w0 + w;
        for (int i = 0; i < 32; i++) {
            int c = (t >> 6) + i * 4;
            sA[w][c] = f2bf(xp[(size_t)c * HW]);
        }
    }
    for (int it = 0; it < 16; it++) {
        int f = it * 1024 + t * 4;
        int o = f >> 7, c = f & 127;
        float4 v = *(const float4*)(wv + o * CC + c);
        sB[o][c] = f2bf(v.x); sB[o][c + 1] = f2bf(v.y);
        sB[o][c + 2] = f2bf(v.z); sB[o][c + 3] = f2bf(v.w);
    }
    __syncthreads();
    const int wid = t >> 6, l = t & 63, lr = l & 15, lg = l >> 4;
    f32x4 acc[8] = {};
    for (int kk = 0; kk < 4; kk++) {
        bf16x8 a = *(const bf16x8*)&sA[wid * 16 + lr][kk * 32 + lg * 8];
#pragma unroll
        for (int nt = 0; nt < 8; nt++) {
            bf16x8 bb = *(const bf16x8*)&sB[nt * 16 + lr][kk * 32 + lg * 8];
            acc[nt] = MFMA(a, bb, acc[nt]);
        }
    }
    // store V^T: [B,H,C,W]
    unsigned short* vp = vo + ((size_t)(b * HH + h) * CC) * WW + w0;
    for (int nt = 0; nt < 8; nt++) {
        int o = nt * 16 + lr;
        float bias = bv[o];
        u16x4 u;
        u[0] = f2bf(acc[nt][0] + bias);
        u[1] = f2bf(acc[nt][1] + bias);
        u[2] = f2bf(acc[nt][2] + bias);
        u[3] = f2bf(acc[nt][3] + bias);
        *(u16x4*)&vp[(size_t)o * WW + wid * 16 + lg * 4] = u;
    }
}

// ---------------- K = dilated 3x3 conv (dilation 4, pad 4) over N -> [B,H,W,C] bf16
__global__ __launch_bounds__(256) void dconv_k(
    const unsigned short* __restrict__ ntl, const unsigned short* __restrict__ ntr,
    const unsigned short* __restrict__ wd,
    const float* __restrict__ dlb, const float* __restrict__ drb,
    unsigned short* __restrict__ klo, unsigned short* __restrict__ kro)
{
    const int side = blockIdx.y;
    const unsigned short* nt = side ? ntr : ntl;
    const unsigned short* wdp = wd + (size_t)side * 9 * CC * CC;
    const float* bd = side ? drb : dlb;
    unsigned short* ko = side ? kro : klo;
    const int bid = blockIdx.x;
    const int wt = bid & 7, h = (bid >> 3) % HH, b = bid / (8 * HH);
    const int w0 = wt * 64;
    const int t = threadIdx.x;
    const int wid = t >> 6, l = t & 63, lr = l & 15, lg = l >> 4;

    __shared__ unsigned short sA[72][136];    // one dy-row of N, w0-4 .. w0+67
    __shared__ unsigned short sB[128][136];   // one tap's weights [o][c]

    f32x4 acc[8] = {};
    for (int dy = 0; dy < 3; dy++) {
        const int hh = h + 4 * (dy - 1);
        const bool hok = (hh >= 0 && hh < HH);
        __syncthreads();
        for (int f = t * 8; f < 72 * 128; f += 2048) {
            int wloc = f >> 7, c = f & 127;
            int w = w0 - 4 + wloc;
            bf16x8 v = {0, 0, 0, 0, 0, 0, 0, 0};
            if (hok && w >= 0 && w < WW)
                v = *(const bf16x8*)(nt + ((size_t)(b * HH + hh) * WW + w) * CC + c);
            *(bf16x8*)&sA[wloc][c] = v;
        }
        for (int dx = 0; dx < 3; dx++) {
            __syncthreads();
            const int tap = dy * 3 + dx;
            for (int it = 0; it < 8; it++) {
                int f = it * 2048 + t * 8;
                *(bf16x8*)&sB[f >> 7][f & 127] =
                    *(const bf16x8*)(wdp + (size_t)tap * CC * CC + f);
            }
            __syncthreads();
            const int arow = wid * 16 + lr + 4 * dx;
            for (int kk = 0; kk < 4; kk++) {
                bf16x8 a = *(const bf16x8*)&sA[arow][kk * 32 + lg * 8];
#pragma unroll
                for (int nt_ = 0; nt_ < 8; nt_++) {
                    bf16x8 bb = *(const bf16x8*)&sB[nt_ * 16 + lr][kk * 32 + lg * 8];
                    acc[nt_] = MFMA(a, bb, acc[nt_]);
                }
            }
        }
    }
    unsigned short* kp = ko + ((size_t)(b * HH + h) * WW + w0) * CC;
    for (int nt_ = 0; nt_ < 8; nt_++) {
        int o = nt_ * 16 + lr;
        float bias = bd[o];
        for (int j = 0; j < 4; j++) {
            int w = wid * 16 + lg * 4 + j;
            kp[(size_t)w * CC + o] = f2bf(acc[nt_][j] + bias);
        }
    }
}

// ---------------- fused Q-GEMM + flash attention + residual epilogue
// V is consumed in V^T layout [B,H,C,W] -> no in-kernel transpose.
__global__ __launch_bounds__(256) void attn_k(
    const unsigned short* __restrict__ ntl, const unsigned short* __restrict__ ntr,
    const unsigned short* __restrict__ kl,  const unsigned short* __restrict__ kr,
    const unsigned short* __restrict__ vtl, const unsigned short* __restrict__ vtr,
    const float* __restrict__ lp1w, const float* __restrict__ lp1b,
    const float* __restrict__ rp1w, const float* __restrict__ rp1b,
    const float* __restrict__ xl, const float* __restrict__ xr,
    const float* __restrict__ beta, const float* __restrict__ gamma,
    float* __restrict__ out)
{
    __shared__ __align__(16) char smem[62464];
    unsigned short* sQ  = (unsigned short*)smem;             // [64][136]
    unsigned short* sW  = (unsigned short*)(smem + 17408);   // [128][136] phase A only
    unsigned short* sKt = sW;                                // [64][136] phase B
    unsigned short* sVt = (unsigned short*)(smem + 34816);   // [128][72] V^T tile
    unsigned short* sPs = (unsigned short*)(smem + 53248);   // [64][72] P bf16
    float* sOf = (float*)(smem + 17408);                     // [64][129] O fp32 (epilogue)

    const int dir = blockIdx.z;
    const unsigned short* nq  = dir ? ntr : ntl;
    const unsigned short* kws = dir ? kl : kr;
    const unsigned short* vws = dir ? vtl : vtr;
    const float* wq   = dir ? rp1w : lp1w;
    const float* bq   = dir ? rp1b : lp1b;
    const float* xres = dir ? xr : xl;
    const float* mult = dir ? gamma : beta;
    float* op = out + (size_t)dir * TENS;

    // XCD-locality swizzle: 8 q-blocks of one bh land consecutively on one XCD
    const int bid = blockIdx.x;
    const int xcd = bid & 7;
    const int s   = bid >> 3;
    const int qb  = s & 7;
    const int bh  = xcd + 8 * (s >> 3);   // 0..383
    const int q0  = qb * 64;
    const int t = threadIdx.x;
    const int wid = t >> 6, l = t & 63, lr = l & 15, lg = l >> 4;

    const unsigned short* ksrc = kws + (size_t)bh * WW * CC;          // [w][c]
    const unsigned short* vsrc = vws + (size_t)bh * CC * WW;          // [c][w]

    // ---- issue K/V tile-0 global loads early (T14) ----
    bf16x8 kreg[4], vreg[4];
#pragma unroll
    for (int it = 0; it < 4; it++) {
        int f = it * 2048 + t * 8;
        kreg[it] = *(const bf16x8*)(ksrc + f);
    }
#pragma unroll
    for (int it = 0; it < 4; it++) {
        int f = it * 2048 + t * 8;
        int c = f >> 6, k = f & 63;
        vreg[it] = *(const bf16x8*)(vsrc + (size_t)c * WW + k);
    }

    // ---- Phase A: stage N tile + Wq, compute Q = (N*Wq + b) * scale * log2e ----
    {
        const unsigned short* nsrc = nq + ((size_t)bh * WW + q0) * CC;
        for (int it = 0; it < 4; it++) {
            int f = it * 2048 + t * 8;
            *(bf16x8*)&sQ[(f >> 7) * 136 + (f & 127)] = *(const bf16x8*)(nsrc + f);
        }
        for (int it = 0; it < 16; it++) {
            int f = it * 1024 + t * 4;
            int o = f >> 7, c = f & 127;
            float4 v = *(const float4*)(wq + o * CC + c);
            unsigned short* p = &sW[o * 136 + c];
            p[0] = f2bf(v.x); p[1] = f2bf(v.y); p[2] = f2bf(v.z); p[3] = f2bf(v.w);
        }
    }
    __syncthreads();
    f32x4 qacc[8] = {};
    for (int kk = 0; kk < 4; kk++) {
        bf16x8 a = *(const bf16x8*)&sQ[(wid * 16 + lr) * 136 + kk * 32 + lg * 8];
#pragma unroll
        for (int nt = 0; nt < 8; nt++) {
            bf16x8 b = *(const bf16x8*)&sW[(nt * 16 + lr) * 136 + kk * 32 + lg * 8];
            qacc[nt] = MFMA(a, b, qacc[nt]);
        }
    }
    const float SCL = 0.08838834764831845f * 1.4426950408889634f;  // C^-0.5 * log2e
    for (int nt = 0; nt < 8; nt++) {
        float bias = bq[nt * 16 + lr];
        for (int j = 0; j < 4; j++)
            sQ[(wid * 16 + lg * 4 + j) * 136 + nt * 16 + lr] =
                f2bf((qacc[nt][j] + bias) * SCL);
    }
    __syncthreads();
    bf16x8 qf[4];
#pragma unroll
    for (int kk = 0; kk < 4; kk++)
        qf[kk] = *(const bf16x8*)&sQ[(wid * 16 + lr) * 136 + kk * 32 + lg * 8];

    // ---- Phase B: online-softmax attention over 8 KV tiles of 64 ----
    f32x4 oacc[8] = {};
    float mrow[4] = {-1e30f, -1e30f, -1e30f, -1e30f};
    float lrow[4] = {0.f, 0.f, 0.f, 0.f};

    for (int kb = 0; kb < 8; kb++) {
        __syncthreads();   // prior reads of sKt/sVt (or sQ/sW in phase A) complete
        // write staged tile to LDS
#pragma unroll
        for (int it = 0; it < 4; it++) {
            int f = it * 2048 + t * 8;
            *(bf16x8*)&sKt[(f >> 7) * 136 + (f & 127)] = kreg[it];
        }
#pragma unroll
        for (int it = 0; it < 4; it++) {
            int f = it * 2048 + t * 8;
            int c = f >> 6, k = f & 63;
            *(bf16x8*)&sVt[c * 72 + k] = vreg[it];
        }
        // issue next-tile loads (latency hides under QK^T + softmax + PV)
        if (kb < 7) {
#pragma unroll
            for (int it = 0; it < 4; it++) {
                int f = it * 2048 + t * 8;
                kreg[it] = *(const bf16x8*)(ksrc + (kb + 1) * 64 * CC + f);
            }
#pragma unroll
            for (int it = 0; it < 4; it++) {
                int f = it * 2048 + t * 8;
                int c = f >> 6, k = f & 63;
                vreg[it] = *(const bf16x8*)(vsrc + (size_t)c * WW + (kb + 1) * 64 + k);
            }
        }
        __syncthreads();
        f32x4 sacc[4] = {};
        __builtin_amdgcn_s_setprio(1);
        for (int kk = 0; kk < 4; kk++)
#pragma unroll
            for (int nt = 0; nt < 4; nt++) {
                bf16x8 b = *(const bf16x8*)&sKt[(nt * 16 + lr) * 136 + kk * 32 + lg * 8];
                sacc[nt] = MFMA(qf[kk], b, sacc[nt]);
            }
        __builtin_amdgcn_s_setprio(0);
        float al[4];
        for (int j = 0; j < 4; j++) {
            float mx = fmaxf(fmaxf(sacc[0][j], sacc[1][j]), fmaxf(sacc[2][j], sacc[3][j]));
            for (int d = 1; d < 16; d <<= 1) mx = fmaxf(mx, __shfl_xor(mx, d, 64));
            float mn = fmaxf(mrow[j], mx);
            al[j] = exp2f(mrow[j] - mn);
            mrow[j] = mn;
            float rs = 0.f;
            for (int nt = 0; nt < 4; nt++) {
                float p = exp2f(sacc[nt][j] - mn);
                sacc[nt][j] = p;
                rs += p;
            }
            for (int d = 1; d < 16; d <<= 1) rs += __shfl_xor(rs, d, 64);
            lrow[j] = lrow[j] * al[j] + rs;
        }
        for (int nt = 0; nt < 8; nt++) {
            f32x4 o = oacc[nt];
            o[0] *= al[0]; o[1] *= al[1]; o[2] *= al[2]; o[3] *= al[3];
            oacc[nt] = o;
        }
        for (int nt = 0; nt < 4; nt++)
            for (int j = 0; j < 4; j++)
                sPs[(wid * 16 + lg * 4 + j) * 72 + nt * 16 + lr] = f2bf(sacc[nt][j]);
        __syncthreads();
        __builtin_amdgcn_s_setprio(1);
        for (int kk = 0; kk < 2; kk++) {
            bf16x8 pa = *(const bf16x8*)&sPs[(wid * 16 + lr) * 72 + kk * 32 + lg * 8];
#pragma unroll
            for (int nt = 0; nt < 8; nt++) {
                bf16x8 vb = *(const bf16x8*)&sVt[(nt * 16 + lr) * 72 + kk * 32 + lg * 8];
                oacc[nt] = MFMA(pa, vb, oacc[nt]);
            }
        }
        __builtin_amdgcn_s_setprio(0);
    }

    // ---- epilogue: normalize, transpose through LDS, residual + scale, store ----
    for (int j = 0; j < 4; j++) {
        float inv = 1.f / lrow[j];
        for (int nt = 0; nt < 8; nt++) oacc[nt][j] *= inv;
    }
    __syncthreads();
    for (int nt = 0; nt < 8; nt++)
        for (int j = 0; j < 4; j++)
            sOf[(wid * 16 + lg * 4 + j) * 129 + nt * 16 + lr] = oacc[nt][j];
    __syncthreads();
    const int b = bh / HH, h = bh % HH;
    const float* xp = xres + (size_t)b * CHW + (size_t)h * WW + q0;
    float* outp = op + (size_t)b * CHW + (size_t)h * WW + q0;
    const int w = t & 63;
    for (int i = 0; i < 32; i++) {
        int c = (t >> 6) + i * 4;
        outp[(size_t)c * HW + w] = xp[(size_t)c * HW + w] + sOf[w * 129 + c] * mult[c];
    }
}

extern "C" void kernel_launch(void* const* d_in, const int* in_sizes, int n_in,
                              void* d_out, int out_size, void* d_ws, size_t ws_size,
                              hipStream_t stream)
{
    const float* xl   = (const float*)d_in[0];
    const float* xr   = (const float*)d_in[1];
    const float* nlw  = (const float*)d_in[2];
    const float* nlb  = (const float*)d_in[3];
    const float* nrw  = (const float*)d_in[4];
    const float* nrb  = (const float*)d_in[5];
    const float* lp1w = (const float*)d_in[6];
    const float* lp1b = (const float*)d_in[7];
    const float* rp1w = (const float*)d_in[8];
    const float* rp1b = (const float*)d_in[9];
    const float* dlw  = (const float*)d_in[10];
    const float* dlb  = (const float*)d_in[11];
    const float* drw  = (const float*)d_in[12];
    const float* drb  = (const float*)d_in[13];
    const float* lp2w = (const float*)d_in[14];
    const float* lp2b = (const float*)d_in[15];
    const float* rp2w = (const float*)d_in[16];
    const float* rp2b = (const float*)d_in[17];
    const float* beta = (const float*)d_in[18];
    const float* gamma= (const float*)d_in[19];
    float* out = (float*)d_out;

    unsigned short* ws = (unsigned short*)d_ws;
    const size_t A = (size_t)TENS;
    unsigned short* Ntl = ws;
    unsigned short* Ntr = ws + A;
    unsigned short* Kl  = ws + 2 * A;
    unsigned short* Kr  = ws + 3 * A;
    unsigned short* Vtl = ws + 4 * A;   // [B,H,C,W]
    unsigned short* Vtr = ws + 5 * A;
    unsigned short* Wd  = ws + 6 * A;   // [2][9][128][128] bf16

    wcast_k<<<dim3(1152), 256, 0, stream>>>(dlw, drw, Wd);
    ln_k<<<dim3(3072, 2), 256, 0, stream>>>(xl, xr, nlw, nlb, nrw, nrb, Ntl, Ntr);
    vgemm_k<<<dim3(3072, 2), 256, 0, stream>>>(xl, xr, lp2w, lp2b, rp2w, rp2b, Vtl, Vtr);
    dconv_k<<<dim3(3072, 2), 256, 0, stream>>>(Ntl, Ntr, Wd, dlb, drb, Kl, Kr);
    attn_k<<<dim3(3072, 1, 2), 256, 0, stream>>>(Ntl, Ntr, Kl, Kr, Vtl, Vtr,
        lp1w, lp1b, rp1w, rp1b, xl, xr, beta, gamma, out);
}

// Round 3
// 578.543 us; speedup vs baseline: 1.8201x; 1.3248x over previous
//
#include <hip/hip_runtime.h>
#include <stdint.h>

#define CC 128
#define HH 192
#define WW 512
#define BB 2
#define HW (HH*WW)
#define CHW (CC*HW)
#define TENS (BB*CHW)   // 25165824 elems per [B,C,H,W] tensor

typedef __attribute__((ext_vector_type(8))) short bf16x8;
typedef __attribute__((ext_vector_type(4))) float f32x4;
typedef __attribute__((ext_vector_type(4))) unsigned short u16x4;

__device__ __forceinline__ unsigned short f2bf(float f) {
    union { float f; unsigned u; } v; v.f = f;
    return (unsigned short)((v.u + 0x7FFFu + ((v.u >> 16) & 1u)) >> 16);
}
__device__ __forceinline__ float bf2f(unsigned short u) {
    union { unsigned u; float f; } v; v.u = ((unsigned)u) << 16;
    return v.f;
}
__device__ __forceinline__ uint32_t cvtpk(float lo, float hi) {
    uint32_t r;
    asm("v_cvt_pk_bf16_f32 %0, %1, %2" : "=v"(r) : "v"(lo), "v"(hi));
    return r;
}
__device__ __forceinline__ f32x4 MFMA(bf16x8 a, bf16x8 b, f32x4 c) {
    return __builtin_amdgcn_mfma_f32_16x16x32_bf16(a, b, c, 0, 0, 0);
}

// ---------------- weight transpose: dl_w/dr_w [O][C][3][3] -> [side][tap][o][c] bf16
__global__ __launch_bounds__(256) void wcast_k(
    const float* __restrict__ dlw, const float* __restrict__ drw,
    unsigned short* __restrict__ wd)
{
    int i = blockIdx.x * 256 + threadIdx.x;
    if (i >= 2 * 9 * CC * CC) return;
    int side = i / (9 * CC * CC);
    int r = i % (9 * CC * CC);
    int tap = r / (CC * CC);
    int r2 = r % (CC * CC);
    int o = r2 >> 7, c = r2 & 127;
    const float* src = side ? drw : dlw;
    wd[i] = f2bf(src[((size_t)o * CC + c) * 9 + tap]);
}

// ---------------- fused LayerNorm + V-GEMM: reads x once.
// outputs: Nt [B,H,W,C] bf16, V^T [B,H,C,W] bf16
__global__ __launch_bounds__(256) void lnv_k(
    const float* __restrict__ xl, const float* __restrict__ xr,
    const float* __restrict__ nlw, const float* __restrict__ nlb,
    const float* __restrict__ nrw, const float* __restrict__ nrb,
    const float* __restrict__ wlp, const float* __restrict__ blp,
    const float* __restrict__ wrp, const float* __restrict__ brp,
    unsigned short* __restrict__ ntl, unsigned short* __restrict__ ntr,
    unsigned short* __restrict__ vlo, unsigned short* __restrict__ vro)
{
    const int side = blockIdx.y;
    const float* x  = side ? xr : xl;
    const float* nw = side ? nrw : nlw;
    const float* nb = side ? nrb : nlb;
    const float* wv = side ? wrp : wlp;
    const float* bv = side ? brp : blp;
    unsigned short* nt = side ? ntr : ntl;
    unsigned short* vo = side ? vro : vlo;
    const int bid = blockIdx.x;
    const int wt = bid & 7, h = (bid >> 3) % HH, b = bid / (8 * HH);
    const int w0 = wt * 64;
    const int t = threadIdx.x;

    __shared__ unsigned short sA[64][136];    // x^T tile [w][c] bf16
    __shared__ unsigned short sB[128][136];   // weight [o][c] bf16
    __shared__ float red[8][64];
    __shared__ float smu[64], srs[64];

    {
        const int w = t & 63, cg = t >> 6;
        const float* xp = x + (size_t)b * CHW + (size_t)h * WW + w0 + w;
        float s = 0.f, q = 0.f;
        for (int i = 0; i < 16; i++) {
            int c = cg * 32 + i * 2;
            float v0 = xp[(size_t)c * HW];
            float v1 = xp[(size_t)(c + 1) * HW];
            ushort2 u; u.x = f2bf(v0); u.y = f2bf(v1);
            *(ushort2*)&sA[w][c] = u;
            s += v0 + v1; q += v0 * v0 + v1 * v1;
        }
        red[cg][w] = s; red[4 + cg][w] = q;
    }
    for (int it = 0; it < 16; it++) {
        int f = it * 1024 + t * 4;
        int o = f >> 7, c = f & 127;
        float4 v = *(const float4*)(wv + o * CC + c);
        sB[o][c] = f2bf(v.x); sB[o][c + 1] = f2bf(v.y);
        sB[o][c + 2] = f2bf(v.z); sB[o][c + 3] = f2bf(v.w);
    }
    __syncthreads();
    if (t < 64) {
        float S = red[0][t] + red[1][t] + red[2][t] + red[3][t];
        float Q = red[4][t] + red[5][t] + red[6][t] + red[7][t];
        float mu = S * (1.f / CC);
        float var = fmaxf(Q * (1.f / CC) - mu * mu, 0.f);
        smu[t] = mu; srs[t] = rsqrtf(var + 1e-6f);
    }
    __syncthreads();
    {   // LayerNorm output (from bf16 x in sA)
        const int w = t >> 2, c0 = (t & 3) * 32;
        const float mu = smu[w], rs = srs[w];
        unsigned short* np = nt + ((size_t)(b * HH + h) * WW + w0 + w) * CC;
        for (int i = 0; i < 32; i += 2) {
            int c = c0 + i;
            float v0 = (bf2f(sA[w][c]) - mu) * rs * nw[c] + nb[c];
            float v1 = (bf2f(sA[w][c + 1]) - mu) * rs * nw[c + 1] + nb[c + 1];
            ushort2 u; u.x = f2bf(v0); u.y = f2bf(v1);
            *(ushort2*)&np[c] = u;
        }
    }
    // V GEMM (reads only; no extra barrier needed)
    const int wid = t >> 6, l = t & 63, lr = l & 15, lg = l >> 4;
    f32x4 acc[8] = {};
    for (int kk = 0; kk < 4; kk++) {
        bf16x8 a = *(const bf16x8*)&sA[wid * 16 + lr][kk * 32 + lg * 8];
#pragma unroll
        for (int n_ = 0; n_ < 8; n_++) {
            bf16x8 bb = *(const bf16x8*)&sB[n_ * 16 + lr][kk * 32 + lg * 8];
            acc[n_] = MFMA(a, bb, acc[n_]);
        }
    }
    unsigned short* vp = vo + ((size_t)(b * HH + h) * CC) * WW + w0;
    for (int n_ = 0; n_ < 8; n_++) {
        int o = n_ * 16 + lr;
        float bias = bv[o];
        u16x4 u;
        u[0] = f2bf(acc[n_][0] + bias);
        u[1] = f2bf(acc[n_][1] + bias);
        u[2] = f2bf(acc[n_][2] + bias);
        u[3] = f2bf(acc[n_][3] + bias);
        *(u16x4*)&vp[(size_t)o * WW + wid * 16 + lg * 4] = u;
    }
}

// ---------------- K = dilated 3x3 conv (dilation 4, pad 4) over N -> [B,H,W,C] bf16
// 128-wide output tile: weight staging amortized 2x.
__global__ __launch_bounds__(256) void dconv_k(
    const unsigned short* __restrict__ ntl, const unsigned short* __restrict__ ntr,
    const unsigned short* __restrict__ wd,
    const float* __restrict__ dlb, const float* __restrict__ drb,
    unsigned short* __restrict__ klo, unsigned short* __restrict__ kro)
{
    const int side = blockIdx.y;
    const unsigned short* nt = side ? ntr : ntl;
    const unsigned short* wdp = wd + (size_t)side * 9 * CC * CC;
    const float* bd = side ? drb : dlb;
    unsigned short* ko = side ? kro : klo;
    // bijective XCD swizzle (1536 = 8*192): consecutive logical ids per XCD
    const int bid0 = blockIdx.x;
    const int lgc = (bid0 & 7) * 192 + (bid0 >> 3);
    const int wt = lgc & 3;
    const int hb = lgc >> 2;          // 0..383
    const int h = hb % HH, b = hb / HH;
    const int w0 = wt * 128;
    const int t = threadIdx.x;
    const int wid = t >> 6, l = t & 63, lr = l & 15, lg = l >> 4;

    __shared__ unsigned short sA[136][136];   // one dy-row of N, w0-4 .. w0+131
    __shared__ unsigned short sB[128][136];   // one tap's weights [o][c]

    f32x4 acc[2][8] = {};
    for (int dy = 0; dy < 3; dy++) {
        const int hh = h + 4 * (dy - 1);
        const bool hok = (hh >= 0 && hh < HH);
        __syncthreads();
        for (int f = t * 8; f < 136 * 128; f += 2048) {
            int wloc = f >> 7, c = f & 127;
            int w = w0 - 4 + wloc;
            bf16x8 v = {0, 0, 0, 0, 0, 0, 0, 0};
            if (hok && w >= 0 && w < WW)
                v = *(const bf16x8*)(nt + ((size_t)(b * HH + hh) * WW + w) * CC + c);
            *(bf16x8*)&sA[wloc][c] = v;
        }
        for (int dx = 0; dx < 3; dx++) {
            __syncthreads();
            const int tap = dy * 3 + dx;
            for (int it = 0; it < 8; it++) {
                int f = it * 2048 + t * 8;
                *(bf16x8*)&sB[f >> 7][f & 127] =
                    *(const bf16x8*)(wdp + (size_t)tap * CC * CC + f);
            }
            __syncthreads();
            const int ar = wid * 16 + lr + 4 * dx;
            for (int kk = 0; kk < 4; kk++) {
                bf16x8 a0 = *(const bf16x8*)&sA[ar][kk * 32 + lg * 8];
                bf16x8 a1 = *(const bf16x8*)&sA[64 + ar][kk * 32 + lg * 8];
#pragma unroll
                for (int n_ = 0; n_ < 8; n_++) {
                    bf16x8 bb = *(const bf16x8*)&sB[n_ * 16 + lr][kk * 32 + lg * 8];
                    acc[0][n_] = MFMA(a0, bb, acc[0][n_]);
                    acc[1][n_] = MFMA(a1, bb, acc[1][n_]);
                }
            }
        }
    }
    unsigned short* kp = ko + ((size_t)(b * HH + h) * WW + w0) * CC;
    for (int mi = 0; mi < 2; mi++)
        for (int n_ = 0; n_ < 8; n_++) {
            int o = n_ * 16 + lr;
            float bias = bd[o];
            for (int j = 0; j < 4; j++) {
                int w = mi * 64 + wid * 16 + lg * 4 + j;
                kp[(size_t)w * CC + o] = f2bf(acc[mi][n_][j] + bias);
            }
        }
}

// ---------------- fused Q-GEMM + flash attention (swapped-operand) + residual epilogue
__global__ __launch_bounds__(256, 3) void attn_k(
    const unsigned short* __restrict__ ntl, const unsigned short* __restrict__ ntr,
    const unsigned short* __restrict__ kl,  const unsigned short* __restrict__ kr,
    const unsigned short* __restrict__ vtl, const unsigned short* __restrict__ vtr,
    const float* __restrict__ lp1w, const float* __restrict__ lp1b,
    const float* __restrict__ rp1w, const float* __restrict__ rp1b,
    const float* __restrict__ xl, const float* __restrict__ xr,
    const float* __restrict__ beta, const float* __restrict__ gamma,
    float* __restrict__ out)
{
    __shared__ __align__(16) char smem[53248];
    unsigned short* sQ  = (unsigned short*)smem;             // [64][136]
    unsigned short* sW  = (unsigned short*)(smem + 17408);   // [128][136] phase A only
    unsigned short* sKt = (unsigned short*)(smem + 17408);   // [64][136] phase B
    unsigned short* sVt = (unsigned short*)(smem + 34816);   // [128][72] V^T tile

    const int dir = blockIdx.z;
    const unsigned short* nq  = dir ? ntr : ntl;
    const unsigned short* kws = dir ? kl : kr;
    const unsigned short* vws = dir ? vtl : vtr;
    const float* wq   = dir ? rp1w : lp1w;
    const float* bq   = dir ? rp1b : lp1b;
    const float* xres = dir ? xr : xl;
    const float* mult = dir ? gamma : beta;
    float* op = out + (size_t)dir * TENS;

    // XCD-locality swizzle: 8 q-blocks of one bh land consecutively on one XCD
    const int bid = blockIdx.x;
    const int xcd = bid & 7;
    const int s   = bid >> 3;
    const int qb  = s & 7;
    const int bh  = xcd + 8 * (s >> 3);   // 0..383
    const int q0  = qb * 64;
    const int t = threadIdx.x;
    const int wid = t >> 6, l = t & 63, lr = l & 15, lg = l >> 4;

    const unsigned short* ksrc = kws + (size_t)bh * WW * CC;          // [w][c]
    const unsigned short* vsrc = vws + (size_t)bh * CC * WW;          // [c][w]

    // ---- issue K/V tile-0 global loads early (T14) ----
    bf16x8 kreg[4], vreg[4];
#pragma unroll
    for (int it = 0; it < 4; it++) {
        int f = it * 2048 + t * 8;
        kreg[it] = *(const bf16x8*)(ksrc + f);
    }
#pragma unroll
    for (int it = 0; it < 4; it++) {
        int f = it * 2048 + t * 8;
        int c = f >> 6, k = f & 63;
        vreg[it] = *(const bf16x8*)(vsrc + (size_t)c * WW + k);
    }

    // ---- Phase A: stage N tile + Wq, compute Q = (N*Wq + b) * scale * log2e ----
    {
        const unsigned short* nsrc = nq + ((size_t)bh * WW + q0) * CC;
        for (int it = 0; it < 4; it++) {
            int f = it * 2048 + t * 8;
            *(bf16x8*)&sQ[(f >> 7) * 136 + (f & 127)] = *(const bf16x8*)(nsrc + f);
        }
        for (int it = 0; it < 16; it++) {
            int f = it * 1024 + t * 4;
            int o = f >> 7, c = f & 127;
            float4 v = *(const float4*)(wq + o * CC + c);
            unsigned short* p = &sW[o * 136 + c];
            p[0] = f2bf(v.x); p[1] = f2bf(v.y); p[2] = f2bf(v.z); p[3] = f2bf(v.w);
        }
    }
    __syncthreads();
    f32x4 qacc[8] = {};
    for (int kk = 0; kk < 4; kk++) {
        bf16x8 a = *(const bf16x8*)&sQ[(wid * 16 + lr) * 136 + kk * 32 + lg * 8];
#pragma unroll
        for (int n_ = 0; n_ < 8; n_++) {
            bf16x8 b = *(const bf16x8*)&sW[(n_ * 16 + lr) * 136 + kk * 32 + lg * 8];
            qacc[n_] = MFMA(a, b, qacc[n_]);
        }
    }
    const float SCL = 0.08838834764831845f * 1.4426950408889634f;  // C^-0.5 * log2e
    for (int n_ = 0; n_ < 8; n_++) {
        float bias = bq[n_ * 16 + lr];
        for (int j = 0; j < 4; j++)
            sQ[(wid * 16 + lg * 4 + j) * 136 + n_ * 16 + lr] =
                f2bf((qacc[n_][j] + bias) * SCL);
    }
    __syncthreads();
    bf16x8 qf[4];
#pragma unroll
    for (int kk = 0; kk < 4; kk++)
        qf[kk] = *(const bf16x8*)&sQ[(wid * 16 + lr) * 136 + kk * 32 + lg * 8];

    // ---- Phase B: online-softmax attention, swapped operands ----
    // QK^T computes D[k][q]: lane holds P[k=nt*16+lg*4+j][q=wid*16+lr] -> row-local softmax
    f32x4 oacc[8] = {};           // O^T[c=n_*16+lg*4+j][q=wid*16+lr]
    float mrow = -1e30f, lrow = 0.f;
    const int src0 = lr + ((l & 16) << 1);   // lr + 32*(lg&1)
    const int src1 = src0 + 16;
    const int hi = lg >> 1;

    for (int kb = 0; kb < 8; kb++) {
        __syncthreads();
#pragma unroll
        for (int it = 0; it < 4; it++) {
            int f = it * 2048 + t * 8;
            *(bf16x8*)&sKt[(f >> 7) * 136 + (f & 127)] = kreg[it];
        }
#pragma unroll
        for (int it = 0; it < 4; it++) {
            int f = it * 2048 + t * 8;
            int c = f >> 6, k = f & 63;
            *(bf16x8*)&sVt[c * 72 + k] = vreg[it];
        }
        if (kb < 7) {
#pragma unroll
            for (int it = 0; it < 4; it++) {
                int f = it * 2048 + t * 8;
                kreg[it] = *(const bf16x8*)(ksrc + (kb + 1) * 64 * CC + f);
            }
#pragma unroll
            for (int it = 0; it < 4; it++) {
                int f = it * 2048 + t * 8;
                int c = f >> 6, k = f & 63;
                vreg[it] = *(const bf16x8*)(vsrc + (size_t)c * WW + (kb + 1) * 64 + k);
            }
        }
        __syncthreads();
        // QK^T swapped: A = K rows (k), B = Q (col=q)
        f32x4 sacc[4] = {};
        __builtin_amdgcn_s_setprio(1);
        for (int kk = 0; kk < 4; kk++)
#pragma unroll
            for (int n_ = 0; n_ < 4; n_++) {
                bf16x8 kf = *(const bf16x8*)&sKt[(n_ * 16 + lr) * 136 + kk * 32 + lg * 8];
                sacc[n_] = MFMA(kf, qf[kk], sacc[n_]);
            }
        __builtin_amdgcn_s_setprio(0);
        // row softmax: lane-local 16 values + 2 cross-lg shuffles
        float pm = sacc[0][0];
#pragma unroll
        for (int n_ = 0; n_ < 4; n_++)
#pragma unroll
            for (int j = 0; j < 4; j++) pm = fmaxf(pm, sacc[n_][j]);
        pm = fmaxf(pm, __shfl_xor(pm, 16, 64));
        pm = fmaxf(pm, __shfl_xor(pm, 32, 64));
        float mn = fmaxf(mrow, pm);
        float al = exp2f(mrow - mn);
        mrow = mn;
        float p[4][4];
        float rs = 0.f;
#pragma unroll
        for (int n_ = 0; n_ < 4; n_++)
#pragma unroll
            for (int j = 0; j < 4; j++) {
                p[n_][j] = exp2f(sacc[n_][j] - mn);
                rs += p[n_][j];
            }
        rs += __shfl_xor(rs, 16, 64);
        rs += __shfl_xor(rs, 32, 64);
        lrow = lrow * al + rs;
#pragma unroll
        for (int n_ = 0; n_ < 8; n_++) {
            f32x4 o = oacc[n_];
            o[0] *= al; o[1] *= al; o[2] *= al; o[3] *= al;
            oacc[n_] = o;
        }
        // pack P to bf16 pairs (k ascending)
        uint32_t pa0 = cvtpk(p[0][0], p[0][1]), pa1 = cvtpk(p[0][2], p[0][3]);
        uint32_t pb0 = cvtpk(p[1][0], p[1][1]), pb1 = cvtpk(p[1][2], p[1][3]);
        uint32_t pc0 = cvtpk(p[2][0], p[2][1]), pc1 = cvtpk(p[2][2], p[2][3]);
        uint32_t pd0 = cvtpk(p[3][0], p[3][1]), pd1 = cvtpk(p[3][2], p[3][3]);
        // PV swapped: A = V^T rows (c), B = P (col=q). Assemble B-frag via bpermute.
        {   // kk = 0: k in [0,32): candidates nt=0 (pa*) / nt=1 (pb*), select by hi
            uint32_t q00 = __shfl(pa0, src0, 64);
            uint32_t q01 = __shfl(pa1, src0, 64);
            uint32_t q02 = __shfl(pa0, src1, 64);
            uint32_t q03 = __shfl(pa1, src1, 64);
            uint32_t q10 = __shfl(pb0, src0, 64);
            uint32_t q11 = __shfl(pb1, src0, 64);
            uint32_t q12 = __shfl(pb0, src1, 64);
            uint32_t q13 = __shfl(pb1, src1, 64);
            union { uint32_t u[4]; bf16x8 v; } pf;
            pf.u[0] = hi ? q10 : q00;
            pf.u[1] = hi ? q11 : q01;
            pf.u[2] = hi ? q12 : q02;
            pf.u[3] = hi ? q13 : q03;
            __builtin_amdgcn_s_setprio(1);
#pragma unroll
            for (int n_ = 0; n_ < 8; n_++) {
                bf16x8 va = *(const bf16x8*)&sVt[(n_ * 16 + lr) * 72 + lg * 8];
                oacc[n_] = MFMA(va, pf.v, oacc[n_]);
            }
            __builtin_amdgcn_s_setprio(0);
        }
        {   // kk = 1: k in [32,64): candidates nt=2 (pc*) / nt=3 (pd*)
            uint32_t q00 = __shfl(pc0, src0, 64);
            uint32_t q01 = __shfl(pc1, src0, 64);
            uint32_t q02 = __shfl(pc0, src1, 64);
            uint32_t q03 = __shfl(pc1, src1, 64);
            uint32_t q10 = __shfl(pd0, src0, 64);
            uint32_t q11 = __shfl(pd1, src0, 64);
            uint32_t q12 = __shfl(pd0, src1, 64);
            uint32_t q13 = __shfl(pd1, src1, 64);
            union { uint32_t u[4]; bf16x8 v; } pf;
            pf.u[0] = hi ? q10 : q00;
            pf.u[1] = hi ? q11 : q01;
            pf.u[2] = hi ? q12 : q02;
            pf.u[3] = hi ? q13 : q03;
            __builtin_amdgcn_s_setprio(1);
#pragma unroll
            for (int n_ = 0; n_ < 8; n_++) {
                bf16x8 va = *(const bf16x8*)&sVt[(n_ * 16 + lr) * 72 + 32 + lg * 8];
                oacc[n_] = MFMA(va, pf.v, oacc[n_]);
            }
            __builtin_amdgcn_s_setprio(0);
        }
    }

    // ---- epilogue: O^T layout is already [c][w] -> direct coalesced store ----
    const float inv = 1.f / lrow;
    const int b = bh / HH, h = bh % HH;
    const int w = q0 + wid * 16 + lr;
    const float* xp = xres + (size_t)b * CHW + (size_t)h * WW + w;
    float* outp = op + (size_t)b * CHW + (size_t)h * WW + w;
#pragma unroll
    for (int n_ = 0; n_ < 8; n_++)
#pragma unroll
        for (int j = 0; j < 4; j++) {
            int c = n_ * 16 + lg * 4 + j;
            outp[(size_t)c * HW] = xp[(size_t)c * HW] + oacc[n_][j] * inv * mult[c];
        }
}

extern "C" void kernel_launch(void* const* d_in, const int* in_sizes, int n_in,
                              void* d_out, int out_size, void* d_ws, size_t ws_size,
                              hipStream_t stream)
{
    const float* xl   = (const float*)d_in[0];
    const float* xr   = (const float*)d_in[1];
    const float* nlw  = (const float*)d_in[2];
    const float* nlb  = (const float*)d_in[3];
    const float* nrw  = (const float*)d_in[4];
    const float* nrb  = (const float*)d_in[5];
    const float* lp1w = (const float*)d_in[6];
    const float* lp1b = (const float*)d_in[7];
    const float* rp1w = (const float*)d_in[8];
    const float* rp1b = (const float*)d_in[9];
    const float* dlw  = (const float*)d_in[10];
    const float* dlb  = (const float*)d_in[11];
    const float* drw  = (const float*)d_in[12];
    const float* drb  = (const float*)d_in[13];
    const float* lp2w = (const float*)d_in[14];
    const float* lp2b = (const float*)d_in[15];
    const float* rp2w = (const float*)d_in[16];
    const float* rp2b = (const float*)d_in[17];
    const float* beta = (const float*)d_in[18];
    const float* gamma= (const float*)d_in[19];
    float* out = (float*)d_out;

    unsigned short* ws = (unsigned short*)d_ws;
    const size_t A = (size_t)TENS;
    unsigned short* Ntl = ws;
    unsigned short* Ntr = ws + A;
    unsigned short* Kl  = ws + 2 * A;
    unsigned short* Kr  = ws + 3 * A;
    unsigned short* Vtl = ws + 4 * A;   // [B,H,C,W]
    unsigned short* Vtr = ws + 5 * A;
    unsigned short* Wd  = ws + 6 * A;   // [2][9][128][128] bf16

    wcast_k<<<dim3(1152), 256, 0, stream>>>(dlw, drw, Wd);
    lnv_k<<<dim3(3072, 2), 256, 0, stream>>>(xl, xr, nlw, nlb, nrw, nrb,
        lp2w, lp2b, rp2w, rp2b, Ntl, Ntr, Vtl, Vtr);
    dconv_k<<<dim3(1536, 2), 256, 0, stream>>>(Ntl, Ntr, Wd, dlb, drb, Kl, Kr);
    attn_k<<<dim3(3072, 1, 2), 256, 0, stream>>>(Ntl, Ntr, Kl, Kr, Vtl, Vtr,
        lp1w, lp1b, rp1w, rp1b, xl, xr, beta, gamma, out);
}

// Round 4
// 547.567 us; speedup vs baseline: 1.9231x; 1.0566x over previous
//
#include <hip/hip_runtime.h>
#include <stdint.h>

#define CC 128
#define HH 192
#define WW 512
#define BB 2
#define HW (HH*WW)
#define CHW (CC*HW)
#define TENS (BB*CHW)   // 25165824 elems per [B,C,H,W] tensor

typedef __attribute__((ext_vector_type(8))) short bf16x8;
typedef __attribute__((ext_vector_type(4))) float f32x4;
typedef __attribute__((ext_vector_type(4))) unsigned short u16x4;

__device__ __forceinline__ unsigned short f2bf(float f) {
    union { float f; unsigned u; } v; v.f = f;
    return (unsigned short)((v.u + 0x7FFFu + ((v.u >> 16) & 1u)) >> 16);
}
__device__ __forceinline__ float bf2f(unsigned short u) {
    union { unsigned u; float f; } v; v.u = ((unsigned)u) << 16;
    return v.f;
}
__device__ __forceinline__ uint32_t cvtpk(float lo, float hi) {
    uint32_t r;
    asm("v_cvt_pk_bf16_f32 %0, %1, %2" : "=v"(r) : "v"(lo), "v"(hi));
    return r;
}
__device__ __forceinline__ f32x4 MFMA(bf16x8 a, bf16x8 b, f32x4 c) {
    return __builtin_amdgcn_mfma_f32_16x16x32_bf16(a, b, c, 0, 0, 0);
}

// ---------------- weight transpose: dl_w/dr_w [O][C][3][3] -> [side][tap][o][c] bf16
__global__ __launch_bounds__(256) void wcast_k(
    const float* __restrict__ dlw, const float* __restrict__ drw,
    unsigned short* __restrict__ wd)
{
    int i = blockIdx.x * 256 + threadIdx.x;
    if (i >= 2 * 9 * CC * CC) return;
    int side = i / (9 * CC * CC);
    int r = i % (9 * CC * CC);
    int tap = r / (CC * CC);
    int r2 = r % (CC * CC);
    int o = r2 >> 7, c = r2 & 127;
    const float* src = side ? drw : dlw;
    wd[i] = f2bf(src[((size_t)o * CC + c) * 9 + tap]);
}

// ---------------- fused LayerNorm + V-GEMM: reads x once.
// outputs: Nt [B,H,W,C] bf16, V^T [B,H,C,W] bf16
__global__ __launch_bounds__(256) void lnv_k(
    const float* __restrict__ xl, const float* __restrict__ xr,
    const float* __restrict__ nlw, const float* __restrict__ nlb,
    const float* __restrict__ nrw, const float* __restrict__ nrb,
    const float* __restrict__ wlp, const float* __restrict__ blp,
    const float* __restrict__ wrp, const float* __restrict__ brp,
    unsigned short* __restrict__ ntl, unsigned short* __restrict__ ntr,
    unsigned short* __restrict__ vlo, unsigned short* __restrict__ vro)
{
    const int side = blockIdx.y;
    const float* x  = side ? xr : xl;
    const float* nw = side ? nrw : nlw;
    const float* nb = side ? nrb : nlb;
    const float* wv = side ? wrp : wlp;
    const float* bv = side ? brp : blp;
    unsigned short* nt = side ? ntr : ntl;
    unsigned short* vo = side ? vro : vlo;
    const int bid = blockIdx.x;
    const int wt = bid & 7, h = (bid >> 3) % HH, b = bid / (8 * HH);
    const int w0 = wt * 64;
    const int t = threadIdx.x;

    __shared__ unsigned short sA[64][136];    // x^T tile [w][c] bf16
    __shared__ unsigned short sB[128][136];   // weight [o][c] bf16
    __shared__ float red[8][64];
    __shared__ float smu[64], srs[64];

    {
        const int w = t & 63, cg = t >> 6;
        const float* xp = x + (size_t)b * CHW + (size_t)h * WW + w0 + w;
        float s = 0.f, q = 0.f;
        for (int i = 0; i < 16; i++) {
            int c = cg * 32 + i * 2;
            float v0 = xp[(size_t)c * HW];
            float v1 = xp[(size_t)(c + 1) * HW];
            *(uint32_t*)&sA[w][c] = cvtpk(v0, v1);
            s += v0 + v1; q += v0 * v0 + v1 * v1;
        }
        red[cg][w] = s; red[4 + cg][w] = q;
    }
    for (int it = 0; it < 16; it++) {
        int f = it * 1024 + t * 4;
        int o = f >> 7, c = f & 127;
        float4 v = *(const float4*)(wv + o * CC + c);
        *(uint32_t*)&sB[o][c]     = cvtpk(v.x, v.y);
        *(uint32_t*)&sB[o][c + 2] = cvtpk(v.z, v.w);
    }
    __syncthreads();
    if (t < 64) {
        float S = red[0][t] + red[1][t] + red[2][t] + red[3][t];
        float Q = red[4][t] + red[5][t] + red[6][t] + red[7][t];
        float mu = S * (1.f / CC);
        float var = fmaxf(Q * (1.f / CC) - mu * mu, 0.f);
        smu[t] = mu; srs[t] = rsqrtf(var + 1e-6f);
    }
    __syncthreads();
    {   // LayerNorm output (from bf16 x in sA)
        const int w = t >> 2, c0 = (t & 3) * 32;
        const float mu = smu[w], rs = srs[w];
        unsigned short* np = nt + ((size_t)(b * HH + h) * WW + w0 + w) * CC;
        for (int i = 0; i < 32; i += 2) {
            int c = c0 + i;
            float v0 = (bf2f(sA[w][c]) - mu) * rs * nw[c] + nb[c];
            float v1 = (bf2f(sA[w][c + 1]) - mu) * rs * nw[c + 1] + nb[c + 1];
            *(uint32_t*)&np[c] = cvtpk(v0, v1);
        }
    }
    // V GEMM (reads only; no extra barrier needed)
    const int wid = t >> 6, l = t & 63, lr = l & 15, lg = l >> 4;
    f32x4 acc[8] = {};
    for (int kk = 0; kk < 4; kk++) {
        bf16x8 a = *(const bf16x8*)&sA[wid * 16 + lr][kk * 32 + lg * 8];
#pragma unroll
        for (int n_ = 0; n_ < 8; n_++) {
            bf16x8 bb = *(const bf16x8*)&sB[n_ * 16 + lr][kk * 32 + lg * 8];
            acc[n_] = MFMA(a, bb, acc[n_]);
        }
    }
    unsigned short* vp = vo + ((size_t)(b * HH + h) * CC) * WW + w0;
    for (int n_ = 0; n_ < 8; n_++) {
        int o = n_ * 16 + lr;
        float bias = bv[o];
        uint2 uu;
        uu.x = cvtpk(acc[n_][0] + bias, acc[n_][1] + bias);
        uu.y = cvtpk(acc[n_][2] + bias, acc[n_][3] + bias);
        *(uint2*)&vp[(size_t)o * WW + wid * 16 + lg * 4] = uu;
    }
}

// ---------------- K = dilated 3x3 conv (dilation 4, pad 4) over N -> [B,H,W,C] bf16
// 128-wide output tile; waves partition 64w x 64o (balanced LDS reads).
__global__ __launch_bounds__(256) void dconv_k(
    const unsigned short* __restrict__ ntl, const unsigned short* __restrict__ ntr,
    const unsigned short* __restrict__ wd,
    const float* __restrict__ dlb, const float* __restrict__ drb,
    unsigned short* __restrict__ klo, unsigned short* __restrict__ kro)
{
    const int side = blockIdx.y;
    const unsigned short* nt = side ? ntr : ntl;
    const unsigned short* wdp = wd + (size_t)side * 9 * CC * CC;
    const float* bd = side ? drb : dlb;
    unsigned short* ko = side ? kro : klo;
    // bijective XCD swizzle (1536 = 8*192): consecutive logical ids per XCD
    const int bid0 = blockIdx.x;
    const int lgc = (bid0 & 7) * 192 + (bid0 >> 3);
    const int wt = lgc & 3;
    const int hb = lgc >> 2;          // 0..383
    const int h = hb % HH, b = hb / HH;
    const int w0 = wt * 128;
    const int t = threadIdx.x;
    const int wid = t >> 6, l = t & 63, lr = l & 15, lg = l >> 4;
    const int whalf = wid & 1, ohalf = wid >> 1;

    __shared__ unsigned short sA[136][136];   // one dy-row of N, w0-4 .. w0+131
    __shared__ unsigned short sB[128][136];   // one tap's weights [o][c]

    f32x4 acc[4][4] = {};   // [g: w-subgroup][n: o-subgroup]
    for (int dy = 0; dy < 3; dy++) {
        const int hh = h + 4 * (dy - 1);
        const bool hok = (hh >= 0 && hh < HH);
        __syncthreads();
        for (int f = t * 8; f < 136 * 128; f += 2048) {
            int wloc = f >> 7, c = f & 127;
            int w = w0 - 4 + wloc;
            bf16x8 v = {0, 0, 0, 0, 0, 0, 0, 0};
            if (hok && w >= 0 && w < WW)
                v = *(const bf16x8*)(nt + ((size_t)(b * HH + hh) * WW + w) * CC + c);
            *(bf16x8*)&sA[wloc][c] = v;
        }
        for (int dx = 0; dx < 3; dx++) {
            __syncthreads();
            const int tap = dy * 3 + dx;
            for (int it = 0; it < 8; it++) {
                int f = it * 2048 + t * 8;
                *(bf16x8*)&sB[f >> 7][f & 127] =
                    *(const bf16x8*)(wdp + (size_t)tap * CC * CC + f);
            }
            __syncthreads();
            for (int kk = 0; kk < 4; kk++) {
                bf16x8 af[4], bf_[4];
#pragma unroll
                for (int g = 0; g < 4; g++)
                    af[g] = *(const bf16x8*)&sA[whalf * 64 + g * 16 + lr + 4 * dx][kk * 32 + lg * 8];
#pragma unroll
                for (int n_ = 0; n_ < 4; n_++)
                    bf_[n_] = *(const bf16x8*)&sB[ohalf * 64 + n_ * 16 + lr][kk * 32 + lg * 8];
#pragma unroll
                for (int g = 0; g < 4; g++)
#pragma unroll
                    for (int n_ = 0; n_ < 4; n_++)
                        acc[g][n_] = MFMA(af[g], bf_[n_], acc[g][n_]);
            }
        }
    }
    unsigned short* kp = ko + ((size_t)(b * HH + h) * WW + w0) * CC;
    for (int g = 0; g < 4; g++)
        for (int n_ = 0; n_ < 4; n_++) {
            int o = ohalf * 64 + n_ * 16 + lr;
            float bias = bd[o];
            for (int j = 0; j < 4; j++) {
                int w = whalf * 64 + g * 16 + lg * 4 + j;
                kp[(size_t)w * CC + o] = f2bf(acc[g][n_][j] + bias);
            }
        }
}

// ---------------- fused Q-GEMM + flash attention (swapped-operand, QBLK=128)
__global__ __launch_bounds__(256, 2) void attn_k(
    const unsigned short* __restrict__ ntl, const unsigned short* __restrict__ ntr,
    const unsigned short* __restrict__ kl,  const unsigned short* __restrict__ kr,
    const unsigned short* __restrict__ vtl, const unsigned short* __restrict__ vtr,
    const float* __restrict__ lp1w, const float* __restrict__ lp1b,
    const float* __restrict__ rp1w, const float* __restrict__ rp1b,
    const float* __restrict__ xl, const float* __restrict__ xr,
    const float* __restrict__ beta, const float* __restrict__ gamma,
    float* __restrict__ out)
{
    __shared__ __align__(16) char smem[70656];
    unsigned short* sQ  = (unsigned short*)smem;             // [128][136]
    unsigned short* sW  = (unsigned short*)(smem + 34816);   // [128][136] phase A only
    unsigned short* sKt = (unsigned short*)(smem + 34816);   // [64][136]  phase B
    unsigned short* sVt = (unsigned short*)(smem + 52224);   // [128][72]  V^T tile

    const int dir = blockIdx.z;
    const unsigned short* nq  = dir ? ntr : ntl;
    const unsigned short* kws = dir ? kl : kr;
    const unsigned short* vws = dir ? vtl : vtr;
    const float* wq   = dir ? rp1w : lp1w;
    const float* bq   = dir ? rp1b : lp1b;
    const float* xres = dir ? xr : xl;
    const float* mult = dir ? gamma : beta;
    float* op = out + (size_t)dir * TENS;

    // XCD-locality swizzle: 4 q-blocks of one bh land consecutively on one XCD
    const int bid = blockIdx.x;
    const int xcd = bid & 7;
    const int s   = bid >> 3;         // 0..191
    const int qb  = s & 3;
    const int bh  = xcd + 8 * (s >> 2);   // 0..383
    const int q0  = qb * 128;
    const int t = threadIdx.x;
    const int wid = t >> 6, l = t & 63, lr = l & 15, lg = l >> 4;

    const unsigned short* ksrc = kws + (size_t)bh * WW * CC;          // [w][c]
    const unsigned short* vsrc = vws + (size_t)bh * CC * WW;          // [c][w]

    // ---- issue K/V tile-0 global loads early (T14) ----
    bf16x8 kreg[4], vreg[4];
#pragma unroll
    for (int it = 0; it < 4; it++) {
        int f = it * 2048 + t * 8;
        kreg[it] = *(const bf16x8*)(ksrc + f);
    }
#pragma unroll
    for (int it = 0; it < 4; it++) {
        int f = it * 2048 + t * 8;
        int c = f >> 6, k = f & 63;
        vreg[it] = *(const bf16x8*)(vsrc + (size_t)c * WW + k);
    }

    // ---- Phase A: stage N tile (128 q-rows) + Wq, compute Q = (N*Wq+b)*SCL ----
    {
        const unsigned short* nsrc = nq + ((size_t)bh * WW + q0) * CC;
        for (int it = 0; it < 8; it++) {
            int f = it * 2048 + t * 8;
            *(bf16x8*)&sQ[(f >> 7) * 136 + (f & 127)] = *(const bf16x8*)(nsrc + f);
        }
        for (int it = 0; it < 16; it++) {
            int f = it * 1024 + t * 4;
            int o = f >> 7, c = f & 127;
            float4 v = *(const float4*)(wq + o * CC + c);
            *(uint32_t*)&sW[o * 136 + c]     = cvtpk(v.x, v.y);
            *(uint32_t*)&sW[o * 136 + c + 2] = cvtpk(v.z, v.w);
        }
    }
    __syncthreads();
    {
        f32x4 qacc[2][8] = {};
        for (int kk = 0; kk < 4; kk++) {
            bf16x8 a0 = *(const bf16x8*)&sQ[(wid * 32 + lr) * 136 + kk * 32 + lg * 8];
            bf16x8 a1 = *(const bf16x8*)&sQ[(wid * 32 + 16 + lr) * 136 + kk * 32 + lg * 8];
#pragma unroll
            for (int n_ = 0; n_ < 8; n_++) {
                bf16x8 b = *(const bf16x8*)&sW[(n_ * 16 + lr) * 136 + kk * 32 + lg * 8];
                qacc[0][n_] = MFMA(a0, b, qacc[0][n_]);
                qacc[1][n_] = MFMA(a1, b, qacc[1][n_]);
            }
        }
        const float SCL = 0.08838834764831845f * 1.4426950408889634f;  // C^-0.5 * log2e
        __syncthreads();   // all reads of sQ/sW done before overwrite
#pragma unroll
        for (int mg = 0; mg < 2; mg++)
#pragma unroll
            for (int n_ = 0; n_ < 8; n_++) {
                float bias = bq[n_ * 16 + lr];
#pragma unroll
                for (int j = 0; j < 4; j++)
                    sQ[(wid * 32 + mg * 16 + lg * 4 + j) * 136 + n_ * 16 + lr] =
                        f2bf((qacc[mg][n_][j] + bias) * SCL);
            }
    }
    __syncthreads();
    bf16x8 qf[2][4];
#pragma unroll
    for (int qg = 0; qg < 2; qg++)
#pragma unroll
        for (int kk = 0; kk < 4; kk++)
            qf[qg][kk] = *(const bf16x8*)&sQ[(wid * 32 + qg * 16 + lr) * 136 + kk * 32 + lg * 8];

    // ---- Phase B: online-softmax attention, swapped operands ----
    // lane holds P[k=n*16+lg*4+j][q=wid*32+qg*16+lr] -> row-local softmax per qg
    f32x4 oacc[8][2] = {};           // O^T[c=n*16+lg*4+j][q per qg]
    float mrow[2] = {-1e30f, -1e30f};
    float lrow[2] = {0.f, 0.f};
    const int src0 = lr + ((l & 16) << 1);   // lr + 32*(lg&1)
    const int src1 = src0 + 16;
    const int hi = lg >> 1;

    for (int kb = 0; kb < 8; kb++) {
        __syncthreads();
#pragma unroll
        for (int it = 0; it < 4; it++) {
            int f = it * 2048 + t * 8;
            *(bf16x8*)&sKt[(f >> 7) * 136 + (f & 127)] = kreg[it];
        }
#pragma unroll
        for (int it = 0; it < 4; it++) {
            int f = it * 2048 + t * 8;
            int c = f >> 6, k = f & 63;
            *(bf16x8*)&sVt[c * 72 + k] = vreg[it];
        }
        if (kb < 7) {
#pragma unroll
            for (int it = 0; it < 4; it++) {
                int f = it * 2048 + t * 8;
                kreg[it] = *(const bf16x8*)(ksrc + (kb + 1) * 64 * CC + f);
            }
#pragma unroll
            for (int it = 0; it < 4; it++) {
                int f = it * 2048 + t * 8;
                int c = f >> 6, k = f & 63;
                vreg[it] = *(const bf16x8*)(vsrc + (size_t)c * WW + (kb + 1) * 64 + k);
            }
        }
        __syncthreads();
        // QK^T swapped: A = K rows (k), B = Q (col=q); kf read once per (kk,n_)
        f32x4 sacc[2][4] = {};
        __builtin_amdgcn_s_setprio(1);
        for (int kk = 0; kk < 4; kk++)
#pragma unroll
            for (int n_ = 0; n_ < 4; n_++) {
                bf16x8 kf = *(const bf16x8*)&sKt[(n_ * 16 + lr) * 136 + kk * 32 + lg * 8];
                sacc[0][n_] = MFMA(kf, qf[0][kk], sacc[0][n_]);
                sacc[1][n_] = MFMA(kf, qf[1][kk], sacc[1][n_]);
            }
        __builtin_amdgcn_s_setprio(0);
        // softmax per qg (in place: sacc becomes P)
        float al[2];
#pragma unroll
        for (int qg = 0; qg < 2; qg++) {
            float pm = sacc[qg][0][0];
#pragma unroll
            for (int n_ = 0; n_ < 4; n_++)
#pragma unroll
                for (int j = 0; j < 4; j++) pm = fmaxf(pm, sacc[qg][n_][j]);
            pm = fmaxf(pm, __shfl_xor(pm, 16, 64));
            pm = fmaxf(pm, __shfl_xor(pm, 32, 64));
            float mn = fmaxf(mrow[qg], pm);
            al[qg] = exp2f(mrow[qg] - mn);
            mrow[qg] = mn;
            float rs = 0.f;
#pragma unroll
            for (int n_ = 0; n_ < 4; n_++)
#pragma unroll
                for (int j = 0; j < 4; j++) {
                    float e = exp2f(sacc[qg][n_][j] - mn);
                    sacc[qg][n_][j] = e;
                    rs += e;
                }
            rs += __shfl_xor(rs, 16, 64);
            rs += __shfl_xor(rs, 32, 64);
            lrow[qg] = lrow[qg] * al[qg] + rs;
        }
#pragma unroll
        for (int n_ = 0; n_ < 8; n_++)
#pragma unroll
            for (int qg = 0; qg < 2; qg++) {
                f32x4 o = oacc[n_][qg];
                o[0] *= al[qg]; o[1] *= al[qg]; o[2] *= al[qg]; o[3] *= al[qg];
                oacc[n_][qg] = o;
            }
        // pack P to bf16 pairs: pk[qg][n][word]
        uint32_t pk[2][4][2];
#pragma unroll
        for (int qg = 0; qg < 2; qg++)
#pragma unroll
            for (int n_ = 0; n_ < 4; n_++) {
                pk[qg][n_][0] = cvtpk(sacc[qg][n_][0], sacc[qg][n_][1]);
                pk[qg][n_][1] = cvtpk(sacc[qg][n_][2], sacc[qg][n_][3]);
            }
        // PV swapped: A = V^T rows (c), B = P (col=q); va read once per (kk,n_)
#pragma unroll
        for (int kk = 0; kk < 2; kk++) {
            union { uint32_t u[4]; bf16x8 v; } pf[2];
#pragma unroll
            for (int qg = 0; qg < 2; qg++) {
                uint32_t q00 = __shfl(pk[qg][kk * 2][0],     src0, 64);
                uint32_t q01 = __shfl(pk[qg][kk * 2][1],     src0, 64);
                uint32_t q02 = __shfl(pk[qg][kk * 2][0],     src1, 64);
                uint32_t q03 = __shfl(pk[qg][kk * 2][1],     src1, 64);
                uint32_t q10 = __shfl(pk[qg][kk * 2 + 1][0], src0, 64);
                uint32_t q11 = __shfl(pk[qg][kk * 2 + 1][1], src0, 64);
                uint32_t q12 = __shfl(pk[qg][kk * 2 + 1][0], src1, 64);
                uint32_t q13 = __shfl(pk[qg][kk * 2 + 1][1], src1, 64);
                pf[qg].u[0] = hi ? q10 : q00;
                pf[qg].u[1] = hi ? q11 : q01;
                pf[qg].u[2] = hi ? q12 : q02;
                pf[qg].u[3] = hi ? q13 : q03;
            }
            __builtin_amdgcn_s_setprio(1);
#pragma unroll
            for (int n_ = 0; n_ < 8; n_++) {
                bf16x8 va = *(const bf16x8*)&sVt[(n_ * 16 + lr) * 72 + kk * 32 + lg * 8];
                oacc[n_][0] = MFMA(va, pf[0].v, oacc[n_][0]);
                oacc[n_][1] = MFMA(va, pf[1].v, oacc[n_][1]);
            }
            __builtin_amdgcn_s_setprio(0);
        }
    }

    // ---- epilogue: O^T layout is already [c][w] -> direct coalesced store ----
    const float inv0 = 1.f / lrow[0], inv1 = 1.f / lrow[1];
    const int b = bh / HH, h = bh % HH;
    const int w_0 = q0 + wid * 32 + lr;
    const float* xp0 = xres + (size_t)b * CHW + (size_t)h * WW + w_0;
    float* outp0 = op + (size_t)b * CHW + (size_t)h * WW + w_0;
#pragma unroll
    for (int n_ = 0; n_ < 8; n_++) {
        float4 m4 = *(const float4*)&mult[n_ * 16 + lg * 4];
#pragma unroll
        for (int j = 0; j < 4; j++) {
            int c = n_ * 16 + lg * 4 + j;
            float mj = (&m4.x)[j];
            outp0[(size_t)c * HW]      = xp0[(size_t)c * HW]      + oacc[n_][0][j] * inv0 * mj;
            outp0[(size_t)c * HW + 16] = xp0[(size_t)c * HW + 16] + oacc[n_][1][j] * inv1 * mj;
        }
    }
}

extern "C" void kernel_launch(void* const* d_in, const int* in_sizes, int n_in,
                              void* d_out, int out_size, void* d_ws, size_t ws_size,
                              hipStream_t stream)
{
    const float* xl   = (const float*)d_in[0];
    const float* xr   = (const float*)d_in[1];
    const float* nlw  = (const float*)d_in[2];
    const float* nlb  = (const float*)d_in[3];
    const float* nrw  = (const float*)d_in[4];
    const float* nrb  = (const float*)d_in[5];
    const float* lp1w = (const float*)d_in[6];
    const float* lp1b = (const float*)d_in[7];
    const float* rp1w = (const float*)d_in[8];
    const float* rp1b = (const float*)d_in[9];
    const float* dlw  = (const float*)d_in[10];
    const float* dlb  = (const float*)d_in[11];
    const float* drw  = (const float*)d_in[12];
    const float* drb  = (const float*)d_in[13];
    const float* lp2w = (const float*)d_in[14];
    const float* lp2b = (const float*)d_in[15];
    const float* rp2w = (const float*)d_in[16];
    const float* rp2b = (const float*)d_in[17];
    const float* beta = (const float*)d_in[18];
    const float* gamma= (const float*)d_in[19];
    float* out = (float*)d_out;

    unsigned short* ws = (unsigned short*)d_ws;
    const size_t A = (size_t)TENS;
    unsigned short* Ntl = ws;
    unsigned short* Ntr = ws + A;
    unsigned short* Kl  = ws + 2 * A;
    unsigned short* Kr  = ws + 3 * A;
    unsigned short* Vtl = ws + 4 * A;   // [B,H,C,W]
    unsigned short* Vtr = ws + 5 * A;
    unsigned short* Wd  = ws + 6 * A;   // [2][9][128][128] bf16

    wcast_k<<<dim3(1152), 256, 0, stream>>>(dlw, drw, Wd);
    lnv_k<<<dim3(3072, 2), 256, 0, stream>>>(xl, xr, nlw, nlb, nrw, nrb,
        lp2w, lp2b, rp2w, rp2b, Ntl, Ntr, Vtl, Vtr);
    dconv_k<<<dim3(1536, 2), 256, 0, stream>>>(Ntl, Ntr, Wd, dlb, drb, Kl, Kr);
    attn_k<<<dim3(1536, 1, 2), 256, 0, stream>>>(Ntl, Ntr, Kl, Kr, Vtl, Vtr,
        lp1w, lp1b, rp1w, rp1b, xl, xr, beta, gamma, out);
}